// Round 1
// baseline (182.564 us; speedup 1.0000x reference)
//
#include <hip/hip_runtime.h>
#include <hip/hip_bf16.h>
#include <cstdint>

// ---------------------------------------------------------------------------
// MLPDecoder: logit[e] = relu([zu, zv, |zu-zv|] @ W1 + b1) @ W2 + b2
//   z: [100000,128] f32, edge_index: [2,E] int, W1: [384,128], b1:[128],
//   W2: [128,1], b2:[1].  Output: [E] f32.
// Strategy: bf16 MFMA (16x16x32), fp32 accumulate. Threshold is bf16-scale
// (1.9e-2); expected error ~3e-3.
// ---------------------------------------------------------------------------

typedef __bf16 bf16_t;
typedef __bf16 bf16x8 __attribute__((ext_vector_type(8)));
typedef float  floatx4 __attribute__((ext_vector_type(4)));

#define DIM 128
#define K3 384              // 3*DIM
#define E_TILE 64           // edges per block
#define ROW_ELEMS 392       // 384 + 8 pad (16B) -> 784B row, 2-way-bank-alias only (free)
#define N_KSTEP 12          // 384 / 32
#define N_NTILE 8           // 128 / 16

__device__ inline float bflo(unsigned w) { return __uint_as_float(w << 16); }
__device__ inline float bfhi(unsigned w) { return __uint_as_float(w & 0xffff0000u); }

// --- cast z fp32 -> bf16 ----------------------------------------------------
__global__ void cast_z_kernel(const float* __restrict__ z, bf16_t* __restrict__ zb, int n) {
    int idx = (blockIdx.x * 256 + threadIdx.x) * 8;
    if (idx + 8 > n) return;
    const float4* src = reinterpret_cast<const float4*>(z + idx);
    float4 a = src[0], b = src[1];
    bf16x8 o;
    o[0] = (bf16_t)a.x; o[1] = (bf16_t)a.y; o[2] = (bf16_t)a.z; o[3] = (bf16_t)a.w;
    o[4] = (bf16_t)b.x; o[5] = (bf16_t)b.y; o[6] = (bf16_t)b.z; o[7] = (bf16_t)b.w;
    *reinterpret_cast<bf16x8*>(zb + idx) = o;
}

// --- pack W1 [384,128] f32 row-major -> MFMA B-fragment order bf16 ----------
// frag index f = (kstep*8 + ntile); element j of lane l:
//   B[k = kstep*32 + (l>>4)*8 + j][n = ntile*16 + (l&15)]
// stored lane-contiguous: Wp[f*64 + lane] is a 16B bf16x8.
__global__ void pack_w1_kernel(const float* __restrict__ W1, bf16_t* __restrict__ Wp) {
    int f = blockIdx.x * 256 + threadIdx.x;     // 0 .. 12*8*64-1
    if (f >= N_KSTEP * N_NTILE * 64) return;
    int lane = f & 63;
    int nt   = (f >> 6) & 7;
    int ks   = f >> 9;
    int n  = nt * 16 + (lane & 15);
    int k0 = ks * 32 + (lane >> 4) * 8;
    bf16x8 o;
#pragma unroll
    for (int j = 0; j < 8; ++j) o[j] = (bf16_t)W1[(k0 + j) * DIM + n];
    reinterpret_cast<bf16x8*>(Wp)[f] = o;
}

// --- main fused kernel ------------------------------------------------------
// Block: 256 threads = 4 waves, 64 edges. Wave (wm,wn): wm = wave>>1 handles
// m-tiles {2wm, 2wm+1}, wn = wave&1 handles n-tiles {4wn .. 4wn+3}.
template <bool PRECAST>
__global__ __launch_bounds__(256)
void decode_kernel(const void* __restrict__ zsrc,
                   const int* __restrict__ ei,       // [2*E]
                   const bf16_t* __restrict__ Wp,    // packed W1
                   const float* __restrict__ b1,
                   const float* __restrict__ W2,
                   const float* __restrict__ b2,
                   float* __restrict__ out, int E) {
    __shared__ __align__(16) bf16_t Atile[E_TILE * ROW_ELEMS];  // 50176 B
    __shared__ float red[2][E_TILE];                            // 512 B

    const int tid = threadIdx.x;
    const int ebase = blockIdx.x * E_TILE;

    // ---- stage zu (k 0..127) and zv (k 128..255) into LDS, coalesced ----
    // 128 half-rows of 256B; 16 threads x 16B per half-row; 8 iterations.
#pragma unroll
    for (int i = 0; i < 8; ++i) {
        int half  = i * 16 + (tid >> 4);
        int m     = half >> 1;
        int which = half & 1;
        int e = ebase + m; if (e >= E) e = E - 1;
        int node = ei[which * E + e];
        int l16 = tid & 15;
        bf16_t* dst = &Atile[m * ROW_ELEMS + which * DIM + l16 * 8];
        if (PRECAST) {
            const bf16x8* src = reinterpret_cast<const bf16x8*>(
                (const bf16_t*)zsrc + (size_t)node * DIM + l16 * 8);
            *reinterpret_cast<bf16x8*>(dst) = *src;
        } else {
            const float4* src = reinterpret_cast<const float4*>(
                (const float*)zsrc + (size_t)node * DIM + l16 * 8);
            float4 a = src[0], b = src[1];
            bf16x8 o;
            o[0] = (bf16_t)a.x; o[1] = (bf16_t)a.y; o[2] = (bf16_t)a.z; o[3] = (bf16_t)a.w;
            o[4] = (bf16_t)b.x; o[5] = (bf16_t)b.y; o[6] = (bf16_t)b.z; o[7] = (bf16_t)b.w;
            *reinterpret_cast<bf16x8*>(dst) = o;
        }
    }
    __syncthreads();

    // ---- |zu - zv| -> k 256..383 (1024 chunks of 8 bf16; 4 per thread) ----
#pragma unroll
    for (int i = 0; i < 4; ++i) {
        int chunk = i * 256 + tid;          // 0..1023
        int m  = chunk >> 4;                // 16 chunks per edge
        int cc = (chunk & 15) * 8;
        uint4 au = *reinterpret_cast<const uint4*>(&Atile[m * ROW_ELEMS + cc]);
        uint4 av = *reinterpret_cast<const uint4*>(&Atile[m * ROW_ELEMS + DIM + cc]);
        bf16x8 d;
        d[0] = (bf16_t)fabsf(bflo(au.x) - bflo(av.x));
        d[1] = (bf16_t)fabsf(bfhi(au.x) - bfhi(av.x));
        d[2] = (bf16_t)fabsf(bflo(au.y) - bflo(av.y));
        d[3] = (bf16_t)fabsf(bfhi(au.y) - bfhi(av.y));
        d[4] = (bf16_t)fabsf(bflo(au.z) - bflo(av.z));
        d[5] = (bf16_t)fabsf(bfhi(au.z) - bfhi(av.z));
        d[6] = (bf16_t)fabsf(bflo(au.w) - bflo(av.w));
        d[7] = (bf16_t)fabsf(bfhi(au.w) - bfhi(av.w));
        *reinterpret_cast<bf16x8*>(&Atile[m * ROW_ELEMS + 2 * DIM + cc]) = d;
    }
    __syncthreads();

    // ---- K-loop: MFMA 16x16x32 bf16 ----
    const int wave = tid >> 6, lane = tid & 63;
    const int wm = wave >> 1, wn = wave & 1;
    const int l15 = lane & 15, quad = lane >> 4;

    floatx4 acc[2][4];
#pragma unroll
    for (int mt = 0; mt < 2; ++mt)
#pragma unroll
        for (int nt = 0; nt < 4; ++nt) acc[mt][nt] = (floatx4)0.0f;

    float b1v[4], w2v[4];
#pragma unroll
    for (int nt = 0; nt < 4; ++nt) {
        int n = (wn * 4 + nt) * 16 + l15;
        b1v[nt] = b1[n];
        w2v[nt] = W2[n];
    }

    const bf16x8* WpF = reinterpret_cast<const bf16x8*>(Wp);
#pragma unroll
    for (int ks = 0; ks < N_KSTEP; ++ks) {
        bf16x8 bfrag[4];
#pragma unroll
        for (int nt = 0; nt < 4; ++nt)
            bfrag[nt] = WpF[(ks * N_NTILE + wn * 4 + nt) * 64 + lane];
#pragma unroll
        for (int mt = 0; mt < 2; ++mt) {
            int m = wm * 32 + mt * 16 + l15;
            bf16x8 afrag = *reinterpret_cast<const bf16x8*>(
                &Atile[m * ROW_ELEMS + ks * 32 + quad * 8]);
#pragma unroll
            for (int nt = 0; nt < 4; ++nt)
                acc[mt][nt] = __builtin_amdgcn_mfma_f32_16x16x32_bf16(
                    afrag, bfrag[nt], acc[mt][nt], 0, 0, 0);
        }
    }

    // ---- epilogue: bias + relu + dot(W2) ----
    // C/D layout: n = lane&15, m = quad*4 + reg  (within the 16x16 tile)
    float partial[2][4];
#pragma unroll
    for (int mt = 0; mt < 2; ++mt)
#pragma unroll
        for (int r = 0; r < 4; ++r) {
            float s = 0.f;
#pragma unroll
            for (int nt = 0; nt < 4; ++nt) {
                float h = acc[mt][nt][r] + b1v[nt];
                h = fmaxf(h, 0.f);
                s += h * w2v[nt];
            }
            // butterfly across the 16 lanes holding different n
            s += __shfl_xor(s, 1);
            s += __shfl_xor(s, 2);
            s += __shfl_xor(s, 4);
            s += __shfl_xor(s, 8);
            partial[mt][r] = s;
        }
    if (l15 == 0) {
#pragma unroll
        for (int mt = 0; mt < 2; ++mt)
#pragma unroll
            for (int r = 0; r < 4; ++r) {
                int m = wm * 32 + mt * 16 + quad * 4 + r;
                red[wn][m] = partial[mt][r];
            }
    }
    __syncthreads();

    if (tid < E_TILE) {
        int e = ebase + tid;
        if (e < E) out[e] = red[0][tid] + red[1][tid] + b2[0];
    }
}

// ---------------------------------------------------------------------------
extern "C" void kernel_launch(void* const* d_in, const int* in_sizes, int n_in,
                              void* d_out, int out_size, void* d_ws, size_t ws_size,
                              hipStream_t stream) {
    const float* z  = (const float*)d_in[0];
    const int*   ei = (const int*)d_in[1];
    const float* W1 = (const float*)d_in[2];
    const float* b1 = (const float*)d_in[3];
    const float* W2 = (const float*)d_in[4];
    const float* b2 = (const float*)d_in[5];
    float* out = (float*)d_out;

    const int E  = in_sizes[1] / 2;
    const int zn = in_sizes[0];

    const size_t zb_bytes = (size_t)zn * sizeof(bf16_t);
    const size_t wp_bytes = (size_t)N_KSTEP * N_NTILE * 64 * 16;  // 98304
    const bool precast = ws_size >= zb_bytes + wp_bytes;

    bf16_t* zb = (bf16_t*)d_ws;
    bf16_t* wp = precast ? (bf16_t*)((char*)d_ws + zb_bytes) : (bf16_t*)d_ws;

    hipLaunchKernelGGL(pack_w1_kernel, dim3((N_KSTEP * N_NTILE * 64 + 255) / 256),
                       dim3(256), 0, stream, W1, wp);

    const int nblocks = (E + E_TILE - 1) / E_TILE;
    if (precast) {
        hipLaunchKernelGGL(cast_z_kernel, dim3((zn / 8 + 255) / 256), dim3(256),
                           0, stream, z, zb, zn);
        hipLaunchKernelGGL((decode_kernel<true>), dim3(nblocks), dim3(256), 0,
                           stream, (const void*)zb, ei, wp, b1, W2, b2, out, E);
    } else {
        hipLaunchKernelGGL((decode_kernel<false>), dim3(nblocks), dim3(256), 0,
                           stream, (const void*)z, ei, wp, b1, W2, b2, out, E);
    }
}